// Round 12
// baseline (317.142 us; speedup 1.0000x reference)
//
#include <hip/hip_runtime.h>
#include <stdint.h>

typedef __bf16 bf16;
typedef __attribute__((ext_vector_type(8))) bf16 bf16x8;
typedef __attribute__((ext_vector_type(4))) float f32x4;

#define D 64
#define EPW 32   // edges per wave-tile

__device__ __forceinline__ float silu_f(float x) {
    return x / (1.0f + __expf(-x));
}

// ---------------------------------------------------------------------------
// Fused: node_feat f32 -> bf16 cache + dst histogram + zero agg/out buffer.
// (cnt pre-zeroed by a small memset.)
// ---------------------------------------------------------------------------
__global__ void cvt_hist_kernel(const float* __restrict__ nf, bf16* __restrict__ nfb,
                                const int* __restrict__ edst, int* __restrict__ cnt,
                                float* __restrict__ outz,
                                int total8, int E) {
    const int i = blockIdx.x * blockDim.x + threadIdx.x;
    const int stride = gridDim.x * blockDim.x;
    if (i < total8) {
        f32x4 a = ((const f32x4*)nf)[i*2], b = ((const f32x4*)nf)[i*2 + 1];
        bf16x8 v;
        #pragma unroll
        for (int k = 0; k < 4; ++k) { v[k] = (bf16)a[k]; v[4+k] = (bf16)b[k]; }
        ((bf16x8*)nfb)[i] = v;
    }
    const f32x4 z = {0.f, 0.f, 0.f, 0.f};
    const int total4 = total8 * 2;               // N*D/4 f32x4 elements
    for (int j = i; j < total4; j += stride)
        ((f32x4*)outz)[j] = z;
    for (int e = i; e < E; e += stride)
        atomicAdd(&cnt[edst[e]], 1);
}

// ---------------------------------------------------------------------------
// Single-block exclusive scan over cnt[N] -> cur[N] (validated in R3).
// 1024 threads; each owns a CH-element chunk; Hillis-Steele over partials.
// ---------------------------------------------------------------------------
__global__ void scan_kernel(const int* __restrict__ cnt, int* __restrict__ cur, int N) {
    __shared__ int part[1024];
    const int t  = threadIdx.x;
    const int CH = (N + 1023) >> 10;
    const int base = t * CH;
    int s = 0;
    for (int i = 0; i < CH; ++i) { int idx = base + i; if (idx < N) s += cnt[idx]; }
    part[t] = s;
    __syncthreads();
    for (int off = 1; off < 1024; off <<= 1) {
        int v = (t >= off) ? part[t - off] : 0;
        __syncthreads();
        part[t] += v;
        __syncthreads();
    }
    int run = (t == 0) ? 0 : part[t - 1];
    for (int i = 0; i < CH; ++i) {
        int idx = base + i;
        if (idx < N) { cur[idx] = run; run += cnt[idx]; }
    }
}

// scatter: sde[pos] = (src, dst, e); efeat is NOT permuted.
__global__ void scatter_kernel(const int* __restrict__ esrc, const int* __restrict__ edst,
                               int* __restrict__ cur, int4* __restrict__ sde, int E) {
    const int stride = gridDim.x * blockDim.x;
    for (int e = blockIdx.x * blockDim.x + threadIdx.x; e < E; e += stride) {
        const int d = edst[e];
        const int pos = atomicAdd(&cur[d], 1);
        sde[pos] = make_int4(esrc[e], d, e, 0);
    }
}

// ---------------------------------------------------------------------------
// Edge message MLP (bf16 MFMA) over DST-SORTED edges + in-wave run reduction.
// EXACT R9 structure (best measured: ~122 us): 512-thread / 8-wave blocks
// sharing one weight copy (16 waves/CU), STRIDED tile assignment (co-resident
// waves share the same sorted-dst window -> L2 locality on dst gathers + agg
// lines), next-tile sde-id prefetch. Load order: nfb gathers then efeat.
// K-slot convention k' = 32*ks + 8*(lane>>4) + i for BOTH A and B fragments.
// C/D layout: col = nt*16 + (lane&15), row = 4*(lane>>4) + reg.
// ---------------------------------------------------------------------------
__launch_bounds__(512, 4)
__global__ void mp_edge_sorted_kernel(
    const bf16* __restrict__ nfb,
    const int4* __restrict__ sde,
    const float* __restrict__ efeat,
    const float* __restrict__ W1, const float* __restrict__ b1,
    const float* __restrict__ W2, const float* __restrict__ b2,
    float* __restrict__ agg,
    int E)
{
    __shared__ __align__(16) bf16 W1f[6*4*64*8];   // 24 KB (ks,nt,lane,8)
    __shared__ __align__(16) bf16 W2f[2*4*64*8];   //  8 KB
    __shared__ __align__(16) bf16 HM[8][32*72];    // 36.9 KB hidden/msg overlay
    __shared__ float b1s[D], b2s[D];

    const int t    = threadIdx.x;
    const int lane = t & 63;
    const int w    = t >> 6;        // wave 0..7
    const int g    = lane >> 4;
    const int c    = lane & 15;

    for (int idx = t; idx < 6*4*64; idx += 512) {
        int l = idx & 63, nt = (idx >> 6) & 3, ks = idx >> 8;
        int k0 = ks*32 + (l >> 4)*8, col = nt*16 + (l & 15);
        bf16x8 v;
        #pragma unroll
        for (int i = 0; i < 8; ++i) v[i] = (bf16)W1[(k0 + i)*D + col];
        *(bf16x8*)&W1f[idx*8] = v;
    }
    for (int idx = t; idx < 2*4*64; idx += 512) {
        int l = idx & 63, nt = (idx >> 6) & 3, ks = idx >> 8;
        int k0 = ks*32 + (l >> 4)*8, col = nt*16 + (l & 15);
        bf16x8 v;
        #pragma unroll
        for (int i = 0; i < 8; ++i) v[i] = (bf16)W2[(k0 + i)*D + col];
        *(bf16x8*)&W2f[idx*8] = v;
    }
    if (t < D) { b1s[t] = b1[t]; b2s[t] = b2[t]; }
    __syncthreads();   // weights ready; the ONLY barrier

    bf16* hm = &HM[w][0];
    const int nwt = (E + EPW - 1) / EPW;
    const int t0 = blockIdx.x*8 + w;
    const int tstride = gridDim.x*8;

    // prefetched sorted-ids for the upcoming tile
    int4 nq0 = make_int4(0,0,0,0), nq1 = make_int4(0,0,0,0);
    if (t0 < nwt) {
        nq0 = sde[min(t0*EPW + c,      E - 1)];
        nq1 = sde[min(t0*EPW + 16 + c, E - 1)];
    }

    for (int tile = t0; tile < nwt; tile += tstride) {
        const int e0 = tile * EPW;
        const int4 q0 = nq0, q1 = nq1;
        const int tn = tile + tstride;
        if (tn < nwt) {    // prefetch next tile's ids (overlaps this tile)
            nq0 = sde[min(tn*EPW + c,      E - 1)];
            nq1 = sde[min(tn*EPW + 16 + c, E - 1)];
        }
        const int se0 = q0.x, de0 = q0.y, ee0 = q0.z;
        const int se1 = q1.x, de1 = q1.y, ee1 = q1.z;

        // ---- load phase: nfb gathers (bf16, MFMA-ready) + efeat rows (f32) ----
        bf16x8 an[8];
        f32x4  ef[8];
        #pragma unroll
        for (int ks = 0; ks < 4; ++ks) {
            const int row0 = (ks < 2) ? se0 : de0;
            const int row1 = (ks < 2) ? se1 : de1;
            const int coff = (ks & 1)*32 + g*8;
            an[ks*2]   = *(const bf16x8*)&nfb[(size_t)row0*D + coff];
            an[ks*2+1] = *(const bf16x8*)&nfb[(size_t)row1*D + coff];
        }
        #pragma unroll
        for (int ks2 = 0; ks2 < 2; ++ks2) {
            const int coff = ks2*32 + g*8;
            const float* p0 = efeat + (size_t)ee0*D + coff;
            const float* p1 = efeat + (size_t)ee1*D + coff;
            ef[ks2*4+0] = ((const f32x4*)p0)[0];
            ef[ks2*4+1] = ((const f32x4*)p0)[1];
            ef[ks2*4+2] = ((const f32x4*)p1)[0];
            ef[ks2*4+3] = ((const f32x4*)p1)[1];
        }

        // ---- GEMM1: [32,192]@[192,64] ----
        f32x4 acc0[4] = {f32x4{0,0,0,0}, f32x4{0,0,0,0}, f32x4{0,0,0,0}, f32x4{0,0,0,0}};
        f32x4 acc1[4] = {f32x4{0,0,0,0}, f32x4{0,0,0,0}, f32x4{0,0,0,0}, f32x4{0,0,0,0}};
        #pragma unroll
        for (int ks = 0; ks < 4; ++ks) {
            #pragma unroll
            for (int n = 0; n < 4; ++n) {
                bf16x8 bb = *(const bf16x8*)&W1f[((ks*4 + n)*64 + lane)*8];
                acc0[n] = __builtin_amdgcn_mfma_f32_16x16x32_bf16(an[ks*2],   bb, acc0[n], 0, 0, 0);
                acc1[n] = __builtin_amdgcn_mfma_f32_16x16x32_bf16(an[ks*2+1], bb, acc1[n], 0, 0, 0);
            }
        }
        #pragma unroll
        for (int ks2 = 0; ks2 < 2; ++ks2) {
            bf16x8 a0, a1;
            #pragma unroll
            for (int i = 0; i < 4; ++i) {
                a0[i]   = (bf16)ef[ks2*4+0][i];
                a0[4+i] = (bf16)ef[ks2*4+1][i];
                a1[i]   = (bf16)ef[ks2*4+2][i];
                a1[4+i] = (bf16)ef[ks2*4+3][i];
            }
            #pragma unroll
            for (int n = 0; n < 4; ++n) {
                bf16x8 bb = *(const bf16x8*)&W1f[(((ks2+4)*4 + n)*64 + lane)*8];
                acc0[n] = __builtin_amdgcn_mfma_f32_16x16x32_bf16(a0, bb, acc0[n], 0, 0, 0);
                acc1[n] = __builtin_amdgcn_mfma_f32_16x16x32_bf16(a1, bb, acc1[n], 0, 0, 0);
            }
        }

        // ---- bias + SiLU -> per-wave HM (bf16) ----
        #pragma unroll
        for (int n = 0; n < 4; ++n) {
            const int col = n*16 + c;
            const float bias = b1s[col];
            #pragma unroll
            for (int j = 0; j < 4; ++j) {
                hm[(g*4 + j)*72 + col]      = (bf16)silu_f(acc0[n][j] + bias);
                hm[(16 + g*4 + j)*72 + col] = (bf16)silu_f(acc1[n][j] + bias);
            }
        }

        // ---- GEMM2: [32,64]@[64,64] (intra-wave LDS ordering) ----
        f32x4 acc2a[4] = {f32x4{0,0,0,0}, f32x4{0,0,0,0}, f32x4{0,0,0,0}, f32x4{0,0,0,0}};
        f32x4 acc2b[4] = {f32x4{0,0,0,0}, f32x4{0,0,0,0}, f32x4{0,0,0,0}, f32x4{0,0,0,0}};
        #pragma unroll
        for (int ks = 0; ks < 2; ++ks) {
            bf16x8 a0 = *(const bf16x8*)&hm[c*72        + ks*32 + g*8];
            bf16x8 a1 = *(const bf16x8*)&hm[(16 + c)*72 + ks*32 + g*8];
            #pragma unroll
            for (int n = 0; n < 4; ++n) {
                bf16x8 bb = *(const bf16x8*)&W2f[((ks*4 + n)*64 + lane)*8];
                acc2a[n] = __builtin_amdgcn_mfma_f32_16x16x32_bf16(a0, bb, acc2a[n], 0, 0, 0);
                acc2b[n] = __builtin_amdgcn_mfma_f32_16x16x32_bf16(a1, bb, acc2b[n], 0, 0, 0);
            }
        }

        // all GEMM2 hm-reads retired before overwrite (in-wave DS order)
        asm volatile("s_waitcnt lgkmcnt(0)" ::: "memory");

        // ---- messages (+bias) -> HM overlay ----
        #pragma unroll
        for (int n = 0; n < 4; ++n) {
            const int col = n*16 + c;
            const float bias = b2s[col];
            #pragma unroll
            for (int j = 0; j < 4; ++j) {
                hm[(g*4 + j)*72 + col]      = (bf16)(acc2a[n][j] + bias);
                hm[(16 + g*4 + j)*72 + col] = (bf16)(acc2b[n][j] + bias);
            }
        }

        // ---- run detection over the 32 sorted rows ----
        const int da = __shfl(de0, lane & 15);
        const int db = __shfl(de1, lane & 15);
        const int row = lane & 31;
        int rowd = (lane & 16) ? db : da;
        if (e0 + row >= E) rowd = -1;                   // invalid tail rows
        const int prevd = __shfl(rowd, (lane + 63) & 63);
        const bool st = (row == 0) || (rowd != prevd);
        unsigned long long m = __ballot(st) & 0xFFFFFFFFull;

        // ---- per-run column sums (lane = col), one write per run ----
        while (m) {
            const int a = __builtin_ctzll(m); m &= m - 1;
            const int rb = m ? __builtin_ctzll(m) : 32;
            const int d = __shfl(rowd, a);
            if (d >= 0) {
                float s = 0.f;
                for (int r = a; r < rb; ++r) s += (float)hm[r*72 + lane];
                float* dp = &agg[(size_t)d*D + lane];
                if (a > 0 && rb < 32) *dp = s;   // complete run: plain store
                else atomicAdd(dp, s);           // boundary run
            }
        }
    }
}

// ---------------------------------------------------------------------------
// Fallback (ws too small): unsorted f32 edge MLP with atomic scatter-add.
// ---------------------------------------------------------------------------
__launch_bounds__(256, 3)
__global__ void mp_edge_atomic_kernel(
    const float* __restrict__ node_feat,
    const int*   __restrict__ esrc,
    const int*   __restrict__ edst,
    const float* __restrict__ efeat,
    const float* __restrict__ W1, const float* __restrict__ b1,
    const float* __restrict__ W2, const float* __restrict__ b2,
    float* __restrict__ agg,
    int E)
{
    __shared__ __align__(16) bf16 W1f[6*4*64*8];
    __shared__ __align__(16) bf16 W2f[2*4*64*8];
    __shared__ __align__(16) bf16 HM[4][32*72];
    __shared__ float b1s[D], b2s[D];

    const int t    = threadIdx.x;
    const int lane = t & 63;
    const int w    = t >> 6;
    const int g    = lane >> 4;
    const int c    = lane & 15;

    for (int idx = t; idx < 6*4*64; idx += 256) {
        int l = idx & 63, nt = (idx >> 6) & 3, ks = idx >> 8;
        int k0 = ks*32 + (l >> 4)*8, col = nt*16 + (l & 15);
        bf16x8 v;
        #pragma unroll
        for (int i = 0; i < 8; ++i) v[i] = (bf16)W1[(k0 + i)*D + col];
        *(bf16x8*)&W1f[idx*8] = v;
    }
    for (int idx = t; idx < 2*4*64; idx += 256) {
        int l = idx & 63, nt = (idx >> 6) & 3, ks = idx >> 8;
        int k0 = ks*32 + (l >> 4)*8, col = nt*16 + (l & 15);
        bf16x8 v;
        #pragma unroll
        for (int i = 0; i < 8; ++i) v[i] = (bf16)W2[(k0 + i)*D + col];
        *(bf16x8*)&W2f[idx*8] = v;
    }
    if (t < D) { b1s[t] = b1[t]; b2s[t] = b2[t]; }
    __syncthreads();

    bf16* hm = &HM[w][0];
    const int nwt = (E + EPW - 1) / EPW;

    for (int tile = blockIdx.x*4 + w; tile < nwt; tile += gridDim.x*4) {
        const int e0 = tile * EPW;
        const int r0 = min(e0 + c,      E - 1);
        const int r1 = min(e0 + 16 + c, E - 1);
        const int se0 = esrc[r0], de0 = edst[r0];
        const int se1 = esrc[r1], de1 = edst[r1];

        f32x4 acc0[4] = {f32x4{0,0,0,0}, f32x4{0,0,0,0}, f32x4{0,0,0,0}, f32x4{0,0,0,0}};
        f32x4 acc1[4] = {f32x4{0,0,0,0}, f32x4{0,0,0,0}, f32x4{0,0,0,0}, f32x4{0,0,0,0}};
        #pragma unroll
        for (int ks = 0; ks < 6; ++ks) {
            const int col = ks*32 + g*8;
            const float *p0, *p1;
            if (col < 64)       { p0 = node_feat + (size_t)se0*D + col;        p1 = node_feat + (size_t)se1*D + col; }
            else if (col < 128) { p0 = node_feat + (size_t)de0*D + (col - 64); p1 = node_feat + (size_t)de1*D + (col - 64); }
            else                { p0 = efeat + (size_t)r0*D + (col - 128);     p1 = efeat + (size_t)r1*D + (col - 128); }
            f32x4 xa = ((const f32x4*)p0)[0], xb = ((const f32x4*)p0)[1];
            f32x4 ya = ((const f32x4*)p1)[0], yb = ((const f32x4*)p1)[1];
            bf16x8 a0, a1;
            #pragma unroll
            for (int i = 0; i < 4; ++i) {
                a0[i] = (bf16)xa[i];  a0[4+i] = (bf16)xb[i];
                a1[i] = (bf16)ya[i];  a1[4+i] = (bf16)yb[i];
            }
            #pragma unroll
            for (int n = 0; n < 4; ++n) {
                bf16x8 bb = *(const bf16x8*)&W1f[((ks*4 + n)*64 + lane)*8];
                acc0[n] = __builtin_amdgcn_mfma_f32_16x16x32_bf16(a0, bb, acc0[n], 0, 0, 0);
                acc1[n] = __builtin_amdgcn_mfma_f32_16x16x32_bf16(a1, bb, acc1[n], 0, 0, 0);
            }
        }

        #pragma unroll
        for (int n = 0; n < 4; ++n) {
            const int col = n*16 + c;
            const float bias = b1s[col];
            #pragma unroll
            for (int j = 0; j < 4; ++j) {
                hm[(g*4 + j)*72 + col]      = (bf16)silu_f(acc0[n][j] + bias);
                hm[(16 + g*4 + j)*72 + col] = (bf16)silu_f(acc1[n][j] + bias);
            }
        }

        f32x4 acc2a[4] = {f32x4{0,0,0,0}, f32x4{0,0,0,0}, f32x4{0,0,0,0}, f32x4{0,0,0,0}};
        f32x4 acc2b[4] = {f32x4{0,0,0,0}, f32x4{0,0,0,0}, f32x4{0,0,0,0}, f32x4{0,0,0,0}};
        #pragma unroll
        for (int ks = 0; ks < 2; ++ks) {
            bf16x8 a0 = *(const bf16x8*)&hm[c*72        + ks*32 + g*8];
            bf16x8 a1 = *(const bf16x8*)&hm[(16 + c)*72 + ks*32 + g*8];
            #pragma unroll
            for (int n = 0; n < 4; ++n) {
                bf16x8 bb = *(const bf16x8*)&W2f[((ks*4 + n)*64 + lane)*8];
                acc2a[n] = __builtin_amdgcn_mfma_f32_16x16x32_bf16(a0, bb, acc2a[n], 0, 0, 0);
                acc2b[n] = __builtin_amdgcn_mfma_f32_16x16x32_bf16(a1, bb, acc2b[n], 0, 0, 0);
            }
        }

        #pragma unroll
        for (int j = 0; j < 4; ++j) {
            const int row = g*4 + j;
            const int d0 = __shfl(de0, row);
            const int d1 = __shfl(de1, row);
            const bool ok0 = (e0 + row)      < E;
            const bool ok1 = (e0 + 16 + row) < E;
            #pragma unroll
            for (int n = 0; n < 4; ++n) {
                const int col = n*16 + c;
                if (ok0) atomicAdd(&agg[(size_t)d0*D + col], acc2a[n][j] + b2s[col]);
                if (ok1) atomicAdd(&agg[(size_t)d1*D + col], acc2b[n][j] + b2s[col]);
            }
        }
    }
}

// ---------------------------------------------------------------------------
// Node update MLP as MFMA GEMM + residual + LayerNorm, in-place on agg.
// ---------------------------------------------------------------------------
__launch_bounds__(256, 4)
__global__ void node_gemm_kernel(
    const float* __restrict__ node_feat,
    const float* __restrict__ Wu1, const float* __restrict__ bu1,
    const float* __restrict__ Wu2, const float* __restrict__ bu2,
    const float* __restrict__ gamma, const float* __restrict__ beta,
    float* __restrict__ inout, int N)
{
    __shared__ __align__(16) bf16 Wf1[2*4*64*8];   // 8 KB
    __shared__ __align__(16) bf16 Wf2[2*4*64*8];   // 8 KB
    __shared__ __align__(16) bf16 Hs[4][16*72];    // 9 KB
    __shared__ float b1s[D], b2s[D], gs[D], bs[D];

    const int t    = threadIdx.x;
    const int lane = t & 63;
    const int w    = t >> 6;
    const int g    = lane >> 4;
    const int c    = lane & 15;

    for (int idx = t; idx < 2*4*64; idx += 256) {
        int l = idx & 63, nt = (idx >> 6) & 3, ks = idx >> 8;
        int k0 = ks*32 + (l >> 4)*8, col = nt*16 + (l & 15);
        bf16x8 v1, v2;
        #pragma unroll
        for (int i = 0; i < 8; ++i) {
            v1[i] = (bf16)Wu1[(k0 + i)*D + col];
            v2[i] = (bf16)Wu2[(k0 + i)*D + col];
        }
        *(bf16x8*)&Wf1[idx*8] = v1;
        *(bf16x8*)&Wf2[idx*8] = v2;
    }
    if (t < D) { b1s[t] = bu1[t]; b2s[t] = bu2[t]; gs[t] = gamma[t]; bs[t] = beta[t]; }
    __syncthreads();

    const int base = blockIdx.x*64 + w*16;
    if (base >= N) return;
    bf16* hs = &Hs[w][0];

    f32x4 acc[4] = {f32x4{0,0,0,0}, f32x4{0,0,0,0}, f32x4{0,0,0,0}, f32x4{0,0,0,0}};
    #pragma unroll
    for (int ks = 0; ks < 2; ++ks) {
        const int rowA = min(base + c, N - 1);
        const float* p = inout + (size_t)rowA*D + ks*32 + g*8;
        f32x4 xa = ((const f32x4*)p)[0], xb = ((const f32x4*)p)[1];
        bf16x8 a;
        #pragma unroll
        for (int i = 0; i < 4; ++i) { a[i] = (bf16)xa[i]; a[4+i] = (bf16)xb[i]; }
        #pragma unroll
        for (int n = 0; n < 4; ++n) {
            bf16x8 bb = *(const bf16x8*)&Wf1[((ks*4 + n)*64 + lane)*8];
            acc[n] = __builtin_amdgcn_mfma_f32_16x16x32_bf16(a, bb, acc[n], 0, 0, 0);
        }
    }
    #pragma unroll
    for (int n = 0; n < 4; ++n) {
        const int col = n*16 + c;
        const float bias = b1s[col];
        #pragma unroll
        for (int j = 0; j < 4; ++j)
            hs[(g*4 + j)*72 + col] = (bf16)silu_f(acc[n][j] + bias);
    }

    f32x4 acc2[4] = {f32x4{0,0,0,0}, f32x4{0,0,0,0}, f32x4{0,0,0,0}, f32x4{0,0,0,0}};
    #pragma unroll
    for (int ks = 0; ks < 2; ++ks) {
        bf16x8 a = *(const bf16x8*)&hs[c*72 + ks*32 + g*8];
        #pragma unroll
        for (int n = 0; n < 4; ++n) {
            bf16x8 bb = *(const bf16x8*)&Wf2[((ks*4 + n)*64 + lane)*8];
            acc2[n] = __builtin_amdgcn_mfma_f32_16x16x32_bf16(a, bb, acc2[n], 0, 0, 0);
        }
    }

    float y[4][4];
    #pragma unroll
    for (int n = 0; n < 4; ++n) {
        const int col = n*16 + c;
        #pragma unroll
        for (int j = 0; j < 4; ++j) {
            const int row = base + g*4 + j;
            const float x0 = (row < N) ? node_feat[(size_t)row*D + col] : 0.f;
            y[n][j] = x0 + acc2[n][j] + b2s[col];
        }
    }
    #pragma unroll
    for (int j = 0; j < 4; ++j) {
        float s1 = 0.f, s2 = 0.f;
        #pragma unroll
        for (int n = 0; n < 4; ++n) { s1 += y[n][j]; s2 += y[n][j]*y[n][j]; }
        #pragma unroll
        for (int mm = 1; mm < 16; mm <<= 1) {
            s1 += __shfl_xor(s1, mm);
            s2 += __shfl_xor(s2, mm);
        }
        const float mu  = s1 * (1.0f/64.0f);
        const float var = s2 * (1.0f/64.0f) - mu*mu;
        const float rs  = rsqrtf(var + 1e-5f);
        const int row = base + g*4 + j;
        if (row < N) {
            #pragma unroll
            for (int n = 0; n < 4; ++n) {
                const int col = n*16 + c;
                inout[(size_t)row*D + col] = (y[n][j] - mu)*rs*gs[col] + bs[col];
            }
        }
    }
}

extern "C" void kernel_launch(void* const* d_in, const int* in_sizes, int n_in,
                              void* d_out, int out_size, void* d_ws, size_t ws_size,
                              hipStream_t stream) {
    const float* node_feat = (const float*)d_in[0];
    const int*   esrc      = (const int*)d_in[1];
    const int*   edst      = (const int*)d_in[2];
    const float* efeat     = (const float*)d_in[3];
    const float* W_m1      = (const float*)d_in[4];
    const float* b_m1      = (const float*)d_in[5];
    const float* W_m2      = (const float*)d_in[6];
    const float* b_m2      = (const float*)d_in[7];
    const float* W_u1      = (const float*)d_in[8];
    const float* b_u1      = (const float*)d_in[9];
    const float* W_u2      = (const float*)d_in[10];
    const float* b_u2      = (const float*)d_in[11];
    const float* ln_gamma  = (const float*)d_in[12];
    const float* ln_beta   = (const float*)d_in[13];

    float* out = (float*)d_out;
    const int E = in_sizes[1];
    const int N = in_sizes[0] / D;

    // ws layout: sde int4[E] | cnt[N] | cur[N] | nfb bf16[N*64]
    const size_t sde_bytes = (((size_t)E * 16) + 255) & ~(size_t)255;
    const size_t int_bytes = ((sizeof(int) * (2*(size_t)N)) + 255) & ~(size_t)255;
    const size_t nfb_bytes = (((size_t)N * D * 2) + 255) & ~(size_t)255;
    const size_t need = sde_bytes + int_bytes + nfb_bytes;

    const int nwt   = (E + EPW - 1) / EPW;
    const int gridN = (N + 63) / 64;

    if (ws_size >= need) {
        int4* sde  = (int4*)d_ws;
        int*  cnt  = (int*)((char*)d_ws + sde_bytes);
        int*  cur  = cnt + N;
        bf16* nfb  = (bf16*)((char*)d_ws + sde_bytes + int_bytes);

        const int total8 = N * D / 8;
        hipMemsetAsync(cnt, 0, sizeof(int)*(size_t)N, stream);
        cvt_hist_kernel<<<(total8 + 255)/256, 256, 0, stream>>>(node_feat, nfb, edst, cnt,
                                                                out, total8, E);
        scan_kernel    <<<1, 1024, 0, stream>>>(cnt, cur, N);
        scatter_kernel <<<1024, 256, 0, stream>>>(esrc, edst, cur, sde, E);

        // 512-thread / 8-wave blocks, 2 blocks/CU -> 16 waves/CU; STRIDED
        // tile assignment (co-resident waves share the sorted-dst window).
        const int nblk8 = (nwt + 7) / 8;
        const int grid1 = nblk8 < 512 ? nblk8 : 512;
        mp_edge_sorted_kernel<<<grid1, 512, 0, stream>>>(nfb, sde, efeat,
                                                         W_m1, b_m1, W_m2, b_m2,
                                                         out, E);
    } else {
        hipMemsetAsync(out, 0, (size_t)N * D * sizeof(float), stream);
        const int nblk4 = (nwt + 3) / 4;
        const int grid1 = nblk4 < 768 ? nblk4 : 768;
        mp_edge_atomic_kernel<<<grid1, 256, 0, stream>>>(node_feat, esrc, edst, efeat,
                                                         W_m1, b_m1, W_m2, b_m2,
                                                         out, E);
    }

    node_gemm_kernel<<<gridN, 256, 0, stream>>>(node_feat, W_u1, b_u1, W_u2, b_u2,
                                                ln_gamma, ln_beta, out, N);
}

// Round 13
// 237.327 us; speedup vs baseline: 1.3363x; 1.3363x over previous
//
#include <hip/hip_runtime.h>
#include <stdint.h>

typedef __bf16 bf16;
typedef __attribute__((ext_vector_type(8))) bf16 bf16x8;
typedef __attribute__((ext_vector_type(4))) float f32x4;

#define D 64
#define EPW 32   // edges per wave-tile

__device__ __forceinline__ float silu_f(float x) {
    return x / (1.0f + __expf(-x));
}

// ---------------------------------------------------------------------------
// cvt node_feat f32 -> bf16 cache; also zeroes cnt[] (runs before hist).
// ---------------------------------------------------------------------------
__global__ void cvt_nf_kernel(const float* __restrict__ nf, bf16* __restrict__ nfb,
                              int* __restrict__ cnt, int total8, int N) {
    const int i = blockIdx.x * blockDim.x + threadIdx.x;
    if (i < total8) {
        f32x4 a = ((const f32x4*)nf)[i*2], b = ((const f32x4*)nf)[i*2 + 1];
        bf16x8 v;
        #pragma unroll
        for (int k = 0; k < 4; ++k) { v[k] = (bf16)a[k]; v[4+k] = (bf16)b[k]; }
        ((bf16x8*)nfb)[i] = v;
    }
    for (int j = blockIdx.x * blockDim.x + threadIdx.x; j < N; j += gridDim.x * blockDim.x)
        cnt[j] = 0;
}

__global__ void hist_kernel(const int* __restrict__ edst, int* __restrict__ cnt, int E) {
    const int stride = gridDim.x * blockDim.x;
    for (int e = blockIdx.x * blockDim.x + threadIdx.x; e < E; e += stride)
        atomicAdd(&cnt[edst[e]], 1);
}

__global__ void scan_part_kernel(const int* __restrict__ cnt, int* __restrict__ part, int N) {
    __shared__ int red[256];
    const int t = threadIdx.x, idx = blockIdx.x * 256 + t;
    red[t] = (idx < N) ? cnt[idx] : 0;
    __syncthreads();
    for (int off = 128; off; off >>= 1) {
        if (t < off) red[t] += red[t + off];
        __syncthreads();
    }
    if (t == 0) part[blockIdx.x] = red[0];
}

__global__ void scan_base_kernel(int* __restrict__ part, int nblk) {
    __shared__ int sc[256];
    const int t = threadIdx.x;
    const int v = (t < nblk) ? part[t] : 0;
    sc[t] = v;
    __syncthreads();
    for (int off = 1; off < 256; off <<= 1) {
        int u = (t >= off) ? sc[t - off] : 0;
        __syncthreads();
        sc[t] += u;
        __syncthreads();
    }
    part[t] = sc[t] - v;   // exclusive base per block
}

// exclusive scan finalize; also zeroes the output/agg buffer (12.8 MB).
__global__ void scan_fin_kernel(const int* __restrict__ cnt, const int* __restrict__ part,
                                int* __restrict__ cur, float* __restrict__ outz, int N) {
    __shared__ int sc[256];
    const int t = threadIdx.x, idx = blockIdx.x * 256 + t;
    const int v = (idx < N) ? cnt[idx] : 0;
    sc[t] = v;
    __syncthreads();
    for (int off = 1; off < 256; off <<= 1) {
        int u = (t >= off) ? sc[t - off] : 0;
        __syncthreads();
        sc[t] += u;
        __syncthreads();
    }
    if (idx < N) {
        cur[idx] = sc[t] - v + part[blockIdx.x];
        f32x4 z = {0.f, 0.f, 0.f, 0.f};
        float* o = outz + (size_t)idx * D;
        #pragma unroll
        for (int i = 0; i < 16; ++i) ((f32x4*)o)[i] = z;
    }
}

// scatter: sde[pos] = (src, dst, e); efeat is NOT permuted.
__global__ void scatter_kernel(const int* __restrict__ esrc, const int* __restrict__ edst,
                               int* __restrict__ cur, int4* __restrict__ sde, int E) {
    const int stride = gridDim.x * blockDim.x;
    for (int e = blockIdx.x * blockDim.x + threadIdx.x; e < E; e += stride) {
        const int d = edst[e];
        const int pos = atomicAdd(&cur[d], 1);
        sde[pos] = make_int4(esrc[e], d, e, 0);
    }
}

// ---------------------------------------------------------------------------
// Edge message MLP (bf16 MFMA) over DST-SORTED edges + in-wave run reduction.
// Best measured config (R9, ~122 us): 512-thread / 8-wave blocks sharing one
// weight copy (16 waves/CU), STRIDED tile assignment (co-resident waves share
// the same sorted-dst window -> L2 locality on dst gathers + agg lines),
// next-tile sde-id prefetch. Load order: nfb gathers then efeat.
// K-slot convention k' = 32*ks + 8*(lane>>4) + i for BOTH A and B fragments.
// C/D layout: col = nt*16 + (lane&15), row = 4*(lane>>4) + reg.
// ---------------------------------------------------------------------------
__launch_bounds__(512, 4)
__global__ void mp_edge_sorted_kernel(
    const bf16* __restrict__ nfb,
    const int4* __restrict__ sde,
    const float* __restrict__ efeat,
    const float* __restrict__ W1, const float* __restrict__ b1,
    const float* __restrict__ W2, const float* __restrict__ b2,
    float* __restrict__ agg,
    int E)
{
    __shared__ __align__(16) bf16 W1f[6*4*64*8];   // 24 KB (ks,nt,lane,8)
    __shared__ __align__(16) bf16 W2f[2*4*64*8];   //  8 KB
    __shared__ __align__(16) bf16 HM[8][32*72];    // 36.9 KB hidden/msg overlay
    __shared__ float b1s[D], b2s[D];

    const int t    = threadIdx.x;
    const int lane = t & 63;
    const int w    = t >> 6;        // wave 0..7
    const int g    = lane >> 4;
    const int c    = lane & 15;

    for (int idx = t; idx < 6*4*64; idx += 512) {
        int l = idx & 63, nt = (idx >> 6) & 3, ks = idx >> 8;
        int k0 = ks*32 + (l >> 4)*8, col = nt*16 + (l & 15);
        bf16x8 v;
        #pragma unroll
        for (int i = 0; i < 8; ++i) v[i] = (bf16)W1[(k0 + i)*D + col];
        *(bf16x8*)&W1f[idx*8] = v;
    }
    for (int idx = t; idx < 2*4*64; idx += 512) {
        int l = idx & 63, nt = (idx >> 6) & 3, ks = idx >> 8;
        int k0 = ks*32 + (l >> 4)*8, col = nt*16 + (l & 15);
        bf16x8 v;
        #pragma unroll
        for (int i = 0; i < 8; ++i) v[i] = (bf16)W2[(k0 + i)*D + col];
        *(bf16x8*)&W2f[idx*8] = v;
    }
    if (t < D) { b1s[t] = b1[t]; b2s[t] = b2[t]; }
    __syncthreads();   // weights ready; the ONLY barrier

    bf16* hm = &HM[w][0];
    const int nwt = (E + EPW - 1) / EPW;
    const int t0 = blockIdx.x*8 + w;
    const int tstride = gridDim.x*8;

    // prefetched sorted-ids for the upcoming tile
    int4 nq0 = make_int4(0,0,0,0), nq1 = make_int4(0,0,0,0);
    if (t0 < nwt) {
        nq0 = sde[min(t0*EPW + c,      E - 1)];
        nq1 = sde[min(t0*EPW + 16 + c, E - 1)];
    }

    for (int tile = t0; tile < nwt; tile += tstride) {
        const int e0 = tile * EPW;
        const int4 q0 = nq0, q1 = nq1;
        const int tn = tile + tstride;
        if (tn < nwt) {    // prefetch next tile's ids (overlaps this tile)
            nq0 = sde[min(tn*EPW + c,      E - 1)];
            nq1 = sde[min(tn*EPW + 16 + c, E - 1)];
        }
        const int se0 = q0.x, de0 = q0.y, ee0 = q0.z;
        const int se1 = q1.x, de1 = q1.y, ee1 = q1.z;

        // ---- load phase: nfb gathers (bf16, MFMA-ready) + efeat rows (f32) ----
        bf16x8 an[8];
        f32x4  ef[8];
        #pragma unroll
        for (int ks = 0; ks < 4; ++ks) {
            const int row0 = (ks < 2) ? se0 : de0;
            const int row1 = (ks < 2) ? se1 : de1;
            const int coff = (ks & 1)*32 + g*8;
            an[ks*2]   = *(const bf16x8*)&nfb[(size_t)row0*D + coff];
            an[ks*2+1] = *(const bf16x8*)&nfb[(size_t)row1*D + coff];
        }
        #pragma unroll
        for (int ks2 = 0; ks2 < 2; ++ks2) {
            const int coff = ks2*32 + g*8;
            const float* p0 = efeat + (size_t)ee0*D + coff;
            const float* p1 = efeat + (size_t)ee1*D + coff;
            ef[ks2*4+0] = ((const f32x4*)p0)[0];
            ef[ks2*4+1] = ((const f32x4*)p0)[1];
            ef[ks2*4+2] = ((const f32x4*)p1)[0];
            ef[ks2*4+3] = ((const f32x4*)p1)[1];
        }

        // ---- GEMM1: [32,192]@[192,64] ----
        f32x4 acc0[4] = {f32x4{0,0,0,0}, f32x4{0,0,0,0}, f32x4{0,0,0,0}, f32x4{0,0,0,0}};
        f32x4 acc1[4] = {f32x4{0,0,0,0}, f32x4{0,0,0,0}, f32x4{0,0,0,0}, f32x4{0,0,0,0}};
        #pragma unroll
        for (int ks = 0; ks < 4; ++ks) {
            #pragma unroll
            for (int n = 0; n < 4; ++n) {
                bf16x8 bb = *(const bf16x8*)&W1f[((ks*4 + n)*64 + lane)*8];
                acc0[n] = __builtin_amdgcn_mfma_f32_16x16x32_bf16(an[ks*2],   bb, acc0[n], 0, 0, 0);
                acc1[n] = __builtin_amdgcn_mfma_f32_16x16x32_bf16(an[ks*2+1], bb, acc1[n], 0, 0, 0);
            }
        }
        #pragma unroll
        for (int ks2 = 0; ks2 < 2; ++ks2) {
            bf16x8 a0, a1;
            #pragma unroll
            for (int i = 0; i < 4; ++i) {
                a0[i]   = (bf16)ef[ks2*4+0][i];
                a0[4+i] = (bf16)ef[ks2*4+1][i];
                a1[i]   = (bf16)ef[ks2*4+2][i];
                a1[4+i] = (bf16)ef[ks2*4+3][i];
            }
            #pragma unroll
            for (int n = 0; n < 4; ++n) {
                bf16x8 bb = *(const bf16x8*)&W1f[(((ks2+4)*4 + n)*64 + lane)*8];
                acc0[n] = __builtin_amdgcn_mfma_f32_16x16x32_bf16(a0, bb, acc0[n], 0, 0, 0);
                acc1[n] = __builtin_amdgcn_mfma_f32_16x16x32_bf16(a1, bb, acc1[n], 0, 0, 0);
            }
        }

        // ---- bias + SiLU -> per-wave HM (bf16) ----
        #pragma unroll
        for (int n = 0; n < 4; ++n) {
            const int col = n*16 + c;
            const float bias = b1s[col];
            #pragma unroll
            for (int j = 0; j < 4; ++j) {
                hm[(g*4 + j)*72 + col]      = (bf16)silu_f(acc0[n][j] + bias);
                hm[(16 + g*4 + j)*72 + col] = (bf16)silu_f(acc1[n][j] + bias);
            }
        }

        // ---- GEMM2: [32,64]@[64,64] (intra-wave LDS ordering) ----
        f32x4 acc2a[4] = {f32x4{0,0,0,0}, f32x4{0,0,0,0}, f32x4{0,0,0,0}, f32x4{0,0,0,0}};
        f32x4 acc2b[4] = {f32x4{0,0,0,0}, f32x4{0,0,0,0}, f32x4{0,0,0,0}, f32x4{0,0,0,0}};
        #pragma unroll
        for (int ks = 0; ks < 2; ++ks) {
            bf16x8 a0 = *(const bf16x8*)&hm[c*72        + ks*32 + g*8];
            bf16x8 a1 = *(const bf16x8*)&hm[(16 + c)*72 + ks*32 + g*8];
            #pragma unroll
            for (int n = 0; n < 4; ++n) {
                bf16x8 bb = *(const bf16x8*)&W2f[((ks*4 + n)*64 + lane)*8];
                acc2a[n] = __builtin_amdgcn_mfma_f32_16x16x32_bf16(a0, bb, acc2a[n], 0, 0, 0);
                acc2b[n] = __builtin_amdgcn_mfma_f32_16x16x32_bf16(a1, bb, acc2b[n], 0, 0, 0);
            }
        }

        // all GEMM2 hm-reads retired before overwrite (in-wave DS order)
        asm volatile("s_waitcnt lgkmcnt(0)" ::: "memory");

        // ---- messages (+bias) -> HM overlay ----
        #pragma unroll
        for (int n = 0; n < 4; ++n) {
            const int col = n*16 + c;
            const float bias = b2s[col];
            #pragma unroll
            for (int j = 0; j < 4; ++j) {
                hm[(g*4 + j)*72 + col]      = (bf16)(acc2a[n][j] + bias);
                hm[(16 + g*4 + j)*72 + col] = (bf16)(acc2b[n][j] + bias);
            }
        }

        // ---- run detection over the 32 sorted rows ----
        const int da = __shfl(de0, lane & 15);
        const int db = __shfl(de1, lane & 15);
        const int row = lane & 31;
        int rowd = (lane & 16) ? db : da;
        if (e0 + row >= E) rowd = -1;                   // invalid tail rows
        const int prevd = __shfl(rowd, (lane + 63) & 63);
        const bool st = (row == 0) || (rowd != prevd);
        unsigned long long m = __ballot(st) & 0xFFFFFFFFull;

        // ---- per-run column sums (lane = col), one write per run ----
        while (m) {
            const int a = __builtin_ctzll(m); m &= m - 1;
            const int rb = m ? __builtin_ctzll(m) : 32;
            const int d = __shfl(rowd, a);
            if (d >= 0) {
                float s = 0.f;
                for (int r = a; r < rb; ++r) s += (float)hm[r*72 + lane];
                float* dp = &agg[(size_t)d*D + lane];
                if (a > 0 && rb < 32) *dp = s;   // complete run: plain store
                else atomicAdd(dp, s);           // boundary run
            }
        }
    }
}

// ---------------------------------------------------------------------------
// Fallback (ws too small): unsorted f32 edge MLP with atomic scatter-add.
// ---------------------------------------------------------------------------
__launch_bounds__(256, 3)
__global__ void mp_edge_atomic_kernel(
    const float* __restrict__ node_feat,
    const int*   __restrict__ esrc,
    const int*   __restrict__ edst,
    const float* __restrict__ efeat,
    const float* __restrict__ W1, const float* __restrict__ b1,
    const float* __restrict__ W2, const float* __restrict__ b2,
    float* __restrict__ agg,
    int E)
{
    __shared__ __align__(16) bf16 W1f[6*4*64*8];
    __shared__ __align__(16) bf16 W2f[2*4*64*8];
    __shared__ __align__(16) bf16 HM[4][32*72];
    __shared__ float b1s[D], b2s[D];

    const int t    = threadIdx.x;
    const int lane = t & 63;
    const int w    = t >> 6;
    const int g    = lane >> 4;
    const int c    = lane & 15;

    for (int idx = t; idx < 6*4*64; idx += 256) {
        int l = idx & 63, nt = (idx >> 6) & 3, ks = idx >> 8;
        int k0 = ks*32 + (l >> 4)*8, col = nt*16 + (l & 15);
        bf16x8 v;
        #pragma unroll
        for (int i = 0; i < 8; ++i) v[i] = (bf16)W1[(k0 + i)*D + col];
        *(bf16x8*)&W1f[idx*8] = v;
    }
    for (int idx = t; idx < 2*4*64; idx += 256) {
        int l = idx & 63, nt = (idx >> 6) & 3, ks = idx >> 8;
        int k0 = ks*32 + (l >> 4)*8, col = nt*16 + (l & 15);
        bf16x8 v;
        #pragma unroll
        for (int i = 0; i < 8; ++i) v[i] = (bf16)W2[(k0 + i)*D + col];
        *(bf16x8*)&W2f[idx*8] = v;
    }
    if (t < D) { b1s[t] = b1[t]; b2s[t] = b2[t]; }
    __syncthreads();

    bf16* hm = &HM[w][0];
    const int nwt = (E + EPW - 1) / EPW;

    for (int tile = blockIdx.x*4 + w; tile < nwt; tile += gridDim.x*4) {
        const int e0 = tile * EPW;
        const int r0 = min(e0 + c,      E - 1);
        const int r1 = min(e0 + 16 + c, E - 1);
        const int se0 = esrc[r0], de0 = edst[r0];
        const int se1 = esrc[r1], de1 = edst[r1];

        f32x4 acc0[4] = {f32x4{0,0,0,0}, f32x4{0,0,0,0}, f32x4{0,0,0,0}, f32x4{0,0,0,0}};
        f32x4 acc1[4] = {f32x4{0,0,0,0}, f32x4{0,0,0,0}, f32x4{0,0,0,0}, f32x4{0,0,0,0}};
        #pragma unroll
        for (int ks = 0; ks < 6; ++ks) {
            const int col = ks*32 + g*8;
            const float *p0, *p1;
            if (col < 64)       { p0 = node_feat + (size_t)se0*D + col;        p1 = node_feat + (size_t)se1*D + col; }
            else if (col < 128) { p0 = node_feat + (size_t)de0*D + (col - 64); p1 = node_feat + (size_t)de1*D + (col - 64); }
            else                { p0 = efeat + (size_t)r0*D + (col - 128);     p1 = efeat + (size_t)r1*D + (col - 128); }
            f32x4 xa = ((const f32x4*)p0)[0], xb = ((const f32x4*)p0)[1];
            f32x4 ya = ((const f32x4*)p1)[0], yb = ((const f32x4*)p1)[1];
            bf16x8 a0, a1;
            #pragma unroll
            for (int i = 0; i < 4; ++i) {
                a0[i] = (bf16)xa[i];  a0[4+i] = (bf16)xb[i];
                a1[i] = (bf16)ya[i];  a1[4+i] = (bf16)yb[i];
            }
            #pragma unroll
            for (int n = 0; n < 4; ++n) {
                bf16x8 bb = *(const bf16x8*)&W1f[((ks*4 + n)*64 + lane)*8];
                acc0[n] = __builtin_amdgcn_mfma_f32_16x16x32_bf16(a0, bb, acc0[n], 0, 0, 0);
                acc1[n] = __builtin_amdgcn_mfma_f32_16x16x32_bf16(a1, bb, acc1[n], 0, 0, 0);
            }
        }

        #pragma unroll
        for (int n = 0; n < 4; ++n) {
            const int col = n*16 + c;
            const float bias = b1s[col];
            #pragma unroll
            for (int j = 0; j < 4; ++j) {
                hm[(g*4 + j)*72 + col]      = (bf16)silu_f(acc0[n][j] + bias);
                hm[(16 + g*4 + j)*72 + col] = (bf16)silu_f(acc1[n][j] + bias);
            }
        }

        f32x4 acc2a[4] = {f32x4{0,0,0,0}, f32x4{0,0,0,0}, f32x4{0,0,0,0}, f32x4{0,0,0,0}};
        f32x4 acc2b[4] = {f32x4{0,0,0,0}, f32x4{0,0,0,0}, f32x4{0,0,0,0}, f32x4{0,0,0,0}};
        #pragma unroll
        for (int ks = 0; ks < 2; ++ks) {
            bf16x8 a0 = *(const bf16x8*)&hm[c*72        + ks*32 + g*8];
            bf16x8 a1 = *(const bf16x8*)&hm[(16 + c)*72 + ks*32 + g*8];
            #pragma unroll
            for (int n = 0; n < 4; ++n) {
                bf16x8 bb = *(const bf16x8*)&W2f[((ks*4 + n)*64 + lane)*8];
                acc2a[n] = __builtin_amdgcn_mfma_f32_16x16x32_bf16(a0, bb, acc2a[n], 0, 0, 0);
                acc2b[n] = __builtin_amdgcn_mfma_f32_16x16x32_bf16(a1, bb, acc2b[n], 0, 0, 0);
            }
        }

        #pragma unroll
        for (int j = 0; j < 4; ++j) {
            const int row = g*4 + j;
            const int d0 = __shfl(de0, row);
            const int d1 = __shfl(de1, row);
            const bool ok0 = (e0 + row)      < E;
            const bool ok1 = (e0 + 16 + row) < E;
            #pragma unroll
            for (int n = 0; n < 4; ++n) {
                const int col = n*16 + c;
                if (ok0) atomicAdd(&agg[(size_t)d0*D + col], acc2a[n][j] + b2s[col]);
                if (ok1) atomicAdd(&agg[(size_t)d1*D + col], acc2b[n][j] + b2s[col]);
            }
        }
    }
}

// ---------------------------------------------------------------------------
// Node update MLP as MFMA GEMM + residual + LayerNorm, in-place on agg.
// ---------------------------------------------------------------------------
__launch_bounds__(256, 4)
__global__ void node_gemm_kernel(
    const float* __restrict__ node_feat,
    const float* __restrict__ Wu1, const float* __restrict__ bu1,
    const float* __restrict__ Wu2, const float* __restrict__ bu2,
    const float* __restrict__ gamma, const float* __restrict__ beta,
    float* __restrict__ inout, int N)
{
    __shared__ __align__(16) bf16 Wf1[2*4*64*8];   // 8 KB
    __shared__ __align__(16) bf16 Wf2[2*4*64*8];   // 8 KB
    __shared__ __align__(16) bf16 Hs[4][16*72];    // 9 KB
    __shared__ float b1s[D], b2s[D], gs[D], bs[D];

    const int t    = threadIdx.x;
    const int lane = t & 63;
    const int w    = t >> 6;
    const int g    = lane >> 4;
    const int c    = lane & 15;

    for (int idx = t; idx < 2*4*64; idx += 256) {
        int l = idx & 63, nt = (idx >> 6) & 3, ks = idx >> 8;
        int k0 = ks*32 + (l >> 4)*8, col = nt*16 + (l & 15);
        bf16x8 v1, v2;
        #pragma unroll
        for (int i = 0; i < 8; ++i) {
            v1[i] = (bf16)Wu1[(k0 + i)*D + col];
            v2[i] = (bf16)Wu2[(k0 + i)*D + col];
        }
        *(bf16x8*)&Wf1[idx*8] = v1;
        *(bf16x8*)&Wf2[idx*8] = v2;
    }
    if (t < D) { b1s[t] = bu1[t]; b2s[t] = bu2[t]; gs[t] = gamma[t]; bs[t] = beta[t]; }
    __syncthreads();

    const int base = blockIdx.x*64 + w*16;
    if (base >= N) return;
    bf16* hs = &Hs[w][0];

    f32x4 acc[4] = {f32x4{0,0,0,0}, f32x4{0,0,0,0}, f32x4{0,0,0,0}, f32x4{0,0,0,0}};
    #pragma unroll
    for (int ks = 0; ks < 2; ++ks) {
        const int rowA = min(base + c, N - 1);
        const float* p = inout + (size_t)rowA*D + ks*32 + g*8;
        f32x4 xa = ((const f32x4*)p)[0], xb = ((const f32x4*)p)[1];
        bf16x8 a;
        #pragma unroll
        for (int i = 0; i < 4; ++i) { a[i] = (bf16)xa[i]; a[4+i] = (bf16)xb[i]; }
        #pragma unroll
        for (int n = 0; n < 4; ++n) {
            bf16x8 bb = *(const bf16x8*)&Wf1[((ks*4 + n)*64 + lane)*8];
            acc[n] = __builtin_amdgcn_mfma_f32_16x16x32_bf16(a, bb, acc[n], 0, 0, 0);
        }
    }
    #pragma unroll
    for (int n = 0; n < 4; ++n) {
        const int col = n*16 + c;
        const float bias = b1s[col];
        #pragma unroll
        for (int j = 0; j < 4; ++j)
            hs[(g*4 + j)*72 + col] = (bf16)silu_f(acc[n][j] + bias);
    }

    f32x4 acc2[4] = {f32x4{0,0,0,0}, f32x4{0,0,0,0}, f32x4{0,0,0,0}, f32x4{0,0,0,0}};
    #pragma unroll
    for (int ks = 0; ks < 2; ++ks) {
        bf16x8 a = *(const bf16x8*)&hs[c*72 + ks*32 + g*8];
        #pragma unroll
        for (int n = 0; n < 4; ++n) {
            bf16x8 bb = *(const bf16x8*)&Wf2[((ks*4 + n)*64 + lane)*8];
            acc2[n] = __builtin_amdgcn_mfma_f32_16x16x32_bf16(a, bb, acc2[n], 0, 0, 0);
        }
    }

    float y[4][4];
    #pragma unroll
    for (int n = 0; n < 4; ++n) {
        const int col = n*16 + c;
        #pragma unroll
        for (int j = 0; j < 4; ++j) {
            const int row = base + g*4 + j;
            const float x0 = (row < N) ? node_feat[(size_t)row*D + col] : 0.f;
            y[n][j] = x0 + acc2[n][j] + b2s[col];
        }
    }
    #pragma unroll
    for (int j = 0; j < 4; ++j) {
        float s1 = 0.f, s2 = 0.f;
        #pragma unroll
        for (int n = 0; n < 4; ++n) { s1 += y[n][j]; s2 += y[n][j]*y[n][j]; }
        #pragma unroll
        for (int mm = 1; mm < 16; mm <<= 1) {
            s1 += __shfl_xor(s1, mm);
            s2 += __shfl_xor(s2, mm);
        }
        const float mu  = s1 * (1.0f/64.0f);
        const float var = s2 * (1.0f/64.0f) - mu*mu;
        const float rs  = rsqrtf(var + 1e-5f);
        const int row = base + g*4 + j;
        if (row < N) {
            #pragma unroll
            for (int n = 0; n < 4; ++n) {
                const int col = n*16 + c;
                inout[(size_t)row*D + col] = (y[n][j] - mu)*rs*gs[col] + bs[col];
            }
        }
    }
}

extern "C" void kernel_launch(void* const* d_in, const int* in_sizes, int n_in,
                              void* d_out, int out_size, void* d_ws, size_t ws_size,
                              hipStream_t stream) {
    const float* node_feat = (const float*)d_in[0];
    const int*   esrc      = (const int*)d_in[1];
    const int*   edst      = (const int*)d_in[2];
    const float* efeat     = (const float*)d_in[3];
    const float* W_m1      = (const float*)d_in[4];
    const float* b_m1      = (const float*)d_in[5];
    const float* W_m2      = (const float*)d_in[6];
    const float* b_m2      = (const float*)d_in[7];
    const float* W_u1      = (const float*)d_in[8];
    const float* b_u1      = (const float*)d_in[9];
    const float* W_u2      = (const float*)d_in[10];
    const float* b_u2      = (const float*)d_in[11];
    const float* ln_gamma  = (const float*)d_in[12];
    const float* ln_beta   = (const float*)d_in[13];

    float* out = (float*)d_out;
    const int E = in_sizes[1];
    const int N = in_sizes[0] / D;

    // ws layout: sde int4[E] | cnt[N] | cur[N] | part[256] | nfb bf16[N*64]
    const size_t sde_bytes = (((size_t)E * 16) + 255) & ~(size_t)255;
    const size_t int_bytes = ((sizeof(int) * (2*(size_t)N + 256)) + 255) & ~(size_t)255;
    const size_t nfb_bytes = (((size_t)N * D * 2) + 255) & ~(size_t)255;
    const size_t need = sde_bytes + int_bytes + nfb_bytes;

    const int nwt    = (E + EPW - 1) / EPW;
    const int gridN  = (N + 63) / 64;
    const int nchunk = (N + 255) / 256;

    if (ws_size >= need) {
        int4* sde  = (int4*)d_ws;
        int*  cnt  = (int*)((char*)d_ws + sde_bytes);
        int*  cur  = cnt + N;
        int*  part = cur + N;
        bf16* nfb  = (bf16*)((char*)d_ws + sde_bytes + int_bytes);

        const int total8 = N * D / 8;
        cvt_nf_kernel   <<<(total8 + 255)/256, 256, 0, stream>>>(node_feat, nfb, cnt, total8, N);
        hist_kernel     <<<1024, 256, 0, stream>>>(edst, cnt, E);
        scan_part_kernel<<<nchunk, 256, 0, stream>>>(cnt, part, N);
        scan_base_kernel<<<1, 256, 0, stream>>>(part, nchunk);
        scan_fin_kernel <<<nchunk, 256, 0, stream>>>(cnt, part, cur, out, N);
        scatter_kernel  <<<1024, 256, 0, stream>>>(esrc, edst, cur, sde, E);

        // 512-thread / 8-wave blocks, 2 blocks/CU -> 16 waves/CU; STRIDED
        // tile assignment (co-resident waves share the sorted-dst window).
        const int nblk8 = (nwt + 7) / 8;
        const int grid1 = nblk8 < 512 ? nblk8 : 512;
        mp_edge_sorted_kernel<<<grid1, 512, 0, stream>>>(nfb, sde, efeat,
                                                         W_m1, b_m1, W_m2, b_m2,
                                                         out, E);
    } else {
        hipMemsetAsync(out, 0, (size_t)N * D * sizeof(float), stream);
        const int nblk4 = (nwt + 3) / 4;
        const int grid1 = nblk4 < 768 ? nblk4 : 768;
        mp_edge_atomic_kernel<<<grid1, 256, 0, stream>>>(node_feat, esrc, edst, efeat,
                                                         W_m1, b_m1, W_m2, b_m2,
                                                         out, E);
    }

    node_gemm_kernel<<<gridN, 256, 0, stream>>>(node_feat, W_u1, b_u1, W_u2, b_u2,
                                                ln_gamma, ln_beta, out, N);
}